// Round 3
// baseline (508.968 us; speedup 1.0000x reference)
//
#include <hip/hip_runtime.h>
#include <hip/hip_bf16.h>
#include <math.h>

#define N 320
#define NN (N * N)          // 102400
#define SST 324             // LDS fp32 row stride for S scratch

typedef float f32x16 __attribute__((ext_vector_type(16)));
typedef short s16x8  __attribute__((ext_vector_type(8)));

#define MFMA32(a, b, c) __builtin_amdgcn_mfma_f32_32x32x16_bf16((a), (b), (c), 0, 0, 0)

union U4V { uint4 q; s16x8 v; };
union UAV { unsigned u[4]; s16x8 v; };

// truncation split: x = hi + lo with hi,lo bf16 (round-toward-zero; rel err ~2^-16 combined)
__device__ inline void split2(float x0, float x1, unsigned& hi, unsigned& lo) {
    unsigned u0 = __float_as_uint(x0), u1 = __float_as_uint(x1);
    hi = (u0 >> 16) | (u1 & 0xFFFF0000u);
    float d0 = x0 - __uint_as_float(u0 & 0xFFFF0000u);
    float d1 = x1 - __uint_as_float(u1 & 0xFFFF0000u);
    lo = (__float_as_uint(d0) >> 16) | (__float_as_uint(d1) & 0xFFFF0000u);
}

// ---------------- fused prep ----------------
// block roles:
//   [  0,100) zero wbuf
//   [100,200) zero out
//   [200,202) colsum[e] = sum_t s[t][e]  (full reduction, no partials)
//   [202,252) pack s^T   (4 sub-blocks of 64 lanes per block)
//   [252,302) pack W^T
__global__ __launch_bounds__(256) void prep_kernel(
    const float* __restrict__ s, const float* __restrict__ W,
    float* __restrict__ wbuf, float* __restrict__ out, float* __restrict__ colsum,
    uint4* __restrict__ spH, uint4* __restrict__ spL,
    uint4* __restrict__ wpH, uint4* __restrict__ wpL)
{
    const int bid = blockIdx.x;
    const int tid = threadIdx.x;
    if (bid < 100) {
        ((float4*)wbuf)[bid * 256 + tid] = make_float4(0.f, 0.f, 0.f, 0.f);
    } else if (bid < 200) {
        ((float4*)out)[(bid - 100) * 256 + tid] = make_float4(0.f, 0.f, 0.f, 0.f);
    } else if (bid < 202) {
        int e = (bid - 200) * 256 + tid;
        if (e < N) {
            const float* sp = s + e;
            float a[8];
#pragma unroll
            for (int u = 0; u < 8; ++u) a[u] = 0.f;
            for (int t = 0; t < N; t += 8) {
#pragma unroll
                for (int u = 0; u < 8; ++u) a[u] += sp[(size_t)(t + u) * N];
            }
            colsum[e] = ((a[0] + a[1]) + (a[2] + a[3])) + ((a[4] + a[5]) + (a[6] + a[7]));
        }
    } else if (bid < 252) {
        int sub = (bid - 202) * 4 + (tid >> 6);     // 0..199 = et*20 + ts
        int l = tid & 63;
        int et = sub / 20, ts = sub % 20;
        int e = et * 32 + (l & 31);
        int t0 = ts * 16 + (l >> 5) * 8;
        unsigned hi[4], lo[4];
#pragma unroll
        for (int d = 0; d < 4; ++d)
            split2(s[(size_t)(t0 + 2 * d) * N + e], s[(size_t)(t0 + 2 * d + 1) * N + e],
                   hi[d], lo[d]);
        spH[sub * 64 + l] = make_uint4(hi[0], hi[1], hi[2], hi[3]);
        spL[sub * 64 + l] = make_uint4(lo[0], lo[1], lo[2], lo[3]);
    } else {
        int sub = (bid - 252) * 4 + (tid >> 6);     // 0..199 = jt*20 + ks
        int l = tid & 63;
        int jt = sub / 20, ks = sub % 20;
        int j = jt * 32 + (l & 31);
        int k0 = ks * 16 + (l >> 5) * 8;
        const float* wr = W + (size_t)j * N + k0;
        unsigned hi[4], lo[4];
#pragma unroll
        for (int d = 0; d < 4; ++d) split2(wr[2 * d], wr[2 * d + 1], hi[d], lo[d]);
        wpH[sub * 64 + l] = make_uint4(hi[0], hi[1], hi[2], hi[3]);
        wpL[sub * 64 + l] = make_uint4(lo[0], lo[1], lo[2], lo[3]);
    }
}

// ---------------- gemm1: G_i = s^T @ F_i, written to global in MFMA-fragment layout ----
// block = (i, e-half): 640 blocks, 10 waves; wave = one 32-wide jj column tile, so
// each F element is loaded+split exactly once per block (2x total chip-wide).
// Per wave: 5 independent 32x32 accumulator tiles stacked in e (160 e rows).
// No barriers: LDS transpose buffer is wave-private.
// G fragment layout (16B units): (((i*10 + eslab)*20 + ks)*2 + hfr)*32 + e31,
// holding A[e][jj] with jj = ks*16 + hfr*8 + m — exactly gemm2's A-operand order.
__global__ __launch_bounds__(640, 2) void gemm1_kernel(
    const float* __restrict__ fut,
    const uint4* __restrict__ spH, const uint4* __restrict__ spL,
    uint4* __restrict__ GH, uint4* __restrict__ GL)
{
    const int bid = blockIdx.x;
    const int i     = bid >> 1;
    const int ehalf = bid & 1;
    const int tid  = threadIdx.x;
    const int wid  = tid >> 6;        // jj tile 0..9
    const int lane = tid & 63;
    const int l31  = lane & 31;
    const int hf   = lane >> 5;

    __shared__ float tb[10][32 * 33];   // per-wave transpose scratch (42240 B)

    f32x16 acc[5];
#pragma unroll
    for (int et = 0; et < 5; ++et)
#pragma unroll
        for (int r = 0; r < 16; ++r) acc[et][r] = 0.f;

    const float* fbase = fut + (size_t)i * NN + (size_t)(hf * 8) * N + wid * 32 + l31;
    const uint4* aH = spH + (size_t)(ehalf * 5 * 20) * 64 + lane;
    const uint4* aL = spL + (size_t)(ehalf * 5 * 20) * 64 + lane;

#pragma unroll 2
    for (int ts = 0; ts < 20; ++ts) {
        const float* fp = fbase + (size_t)(ts * 16) * N;
        float f[8];
#pragma unroll
        for (int m = 0; m < 8; ++m) f[m] = fp[(size_t)m * N];
        UAV bh, bl;
#pragma unroll
        for (int d = 0; d < 4; ++d) split2(f[2 * d], f[2 * d + 1], bh.u[d], bl.u[d]);
#pragma unroll
        for (int et = 0; et < 5; ++et) {
            U4V ah, al;
            ah.q = aH[(et * 20 + ts) * 64];
            al.q = aL[(et * 20 + ts) * 64];
            acc[et] = MFMA32(ah.v, bh.v, acc[et]);
            acc[et] = MFMA32(al.v, bh.v, acc[et]);
            acc[et] = MFMA32(ah.v, bl.v, acc[et]);
        }
    }

    // writeback: per e-tile, transpose (jj-major -> e-major) through wave-private LDS,
    // then split to bf16 hi/lo and store coalesced 16B fragments.
    float* T = &tb[wid][0];
#pragma unroll
    for (int et = 0; et < 5; ++et) {
#pragma unroll
        for (int r = 0; r < 16; ++r) {
            int e = (r & 3) + ((r >> 2) << 3) + (hf << 2);
            T[e * 33 + l31] = acc[et][r];
        }
        // DS ops from one wave execute in order: reads below see the writes above.
        const int eslab = ehalf * 5 + et;
        const int ks = wid * 2 + hf;
#pragma unroll
        for (int u = 0; u < 2; ++u) {
            float x[8];
#pragma unroll
            for (int m = 0; m < 8; ++m) x[m] = T[l31 * 33 + (hf * 2 + u) * 8 + m];
            unsigned hi[4], lo[4];
#pragma unroll
            for (int d = 0; d < 4; ++d) split2(x[2 * d], x[2 * d + 1], hi[d], lo[d]);
            size_t off = ((size_t)((i * 10 + eslab) * 20 + ks) * 2 + u) * 32 + l31;
            GH[off] = make_uint4(hi[0], hi[1], hi[2], hi[3]);
            GL[off] = make_uint4(lo[0], lo[1], lo[2], lo[3]);
        }
    }
}

// ---------------- gemm2: S = G @ W^T (+ colsum*b), softmax rows, w-col accumulate ----
// block = (i, e-slab 32): 3200 blocks. Each G fragment is read exactly once chip-wide.
__global__ __launch_bounds__(640, 6) void gemm2_kernel(
    const uint4* __restrict__ GH, const uint4* __restrict__ GL,
    const uint4* __restrict__ wpH, const uint4* __restrict__ wpL,
    const float* __restrict__ bvec, const float* __restrict__ colsum,
    float* __restrict__ w)
{
    const int bid = blockIdx.x;
    const int i  = bid / 10;
    const int et = bid % 10;
    const int tid = threadIdx.x;
    const int wid = tid >> 6;         // j tile 0..9
    const int lane = tid & 63;
    const int l31 = lane & 31;
    const int hf  = lane >> 5;

    __shared__ float S[32 * SST];     // 41472 B
    __shared__ float csh[32];
    __shared__ float Mfin[32];
    __shared__ float Ifin[32];

    if (tid < 32) csh[tid] = colsum[et * 32 + tid];

    f32x16 p1, p2, p3;
#pragma unroll
    for (int r = 0; r < 16; ++r) { p1[r] = 0.f; p2[r] = 0.f; p3[r] = 0.f; }

    const uint4* gH = GH + ((size_t)(i * 10 + et) * 40 + hf) * 32 + l31;
    const uint4* gL = GL + ((size_t)(i * 10 + et) * 40 + hf) * 32 + l31;
    const uint4* bH = wpH + (size_t)(wid * 20) * 64 + lane;
    const uint4* bL = wpL + (size_t)(wid * 20) * 64 + lane;

#pragma unroll 4
    for (int ks = 0; ks < 20; ++ks) {
        U4V gh, gl, wh, wl;
        gh.q = gH[ks * 64];
        gl.q = gL[ks * 64];
        wh.q = bH[ks * 64];
        wl.q = bL[ks * 64];
        p1 = MFMA32(gh.v, wh.v, p1);
        p2 = MFMA32(gl.v, wh.v, p2);
        p3 = MFMA32(gh.v, wl.v, p3);
    }

    __syncthreads();   // csh visible

    const int jcol = wid * 32 + l31;
    float bj = bvec[jcol];
    float v[16];
#pragma unroll
    for (int r = 0; r < 16; ++r) {
        int e = (r & 3) + ((r >> 2) << 3) + (hf << 2);
        v[r] = (p1[r] + p2[r] + p3[r]) + csh[e] * bj;
        S[e * SST + jcol] = v[r];
    }
    __syncthreads();

    // row sweeps: half-wave hw (0..15) handles rows 2hw, 2hw+1
    const int hw = tid >> 5;
    const int li = tid & 31;
    if (hw < 16) {
#pragma unroll
        for (int rr = 0; rr < 2; ++rr) {
            int row = 2 * hw + rr;
            float x[10];
            float m = -3.4e38f;
#pragma unroll
            for (int q = 0; q < 10; ++q) {
                x[q] = S[row * SST + li + 32 * q];
                m = fmaxf(m, x[q]);
            }
#pragma unroll
            for (int off = 16; off; off >>= 1) m = fmaxf(m, __shfl_xor(m, off, 64));
            float ssum = 0.f;
#pragma unroll
            for (int q = 0; q < 10; ++q) ssum += __expf(x[q] - m);
#pragma unroll
            for (int off = 16; off; off >>= 1) ssum += __shfl_xor(ssum, off, 64);
            if (li == 0) { Mfin[row] = m; Ifin[row] = 1.0f / ssum; }
        }
    }
    __syncthreads();

    float wcol = 0.f;
#pragma unroll
    for (int r = 0; r < 16; ++r) {
        int e = (r & 3) + ((r >> 2) << 3) + (hf << 2);
        wcol += __expf(v[r] - Mfin[e]) * Ifin[e];
    }
    wcol += __shfl_xor(wcol, 32, 64);
    if (hf == 0) atomicAdd(&w[(size_t)i * N + jcol], wcol);
}

// ---------------- fallback (workspace too small for G planes): round-2 fused kernel ----
__global__ __launch_bounds__(640, 3) void fused_fb_kernel(
    const float* __restrict__ fut,
    const uint4* __restrict__ spH, const uint4* __restrict__ spL,
    const uint4* __restrict__ wpH, const uint4* __restrict__ wpL,
    const float* __restrict__ bvec, const float* __restrict__ colsum,
    float* __restrict__ w)
{
    const int bid = blockIdx.x;
    const int i   = (bid / 80) * 8 + (bid & 7);
    const int et  = (bid >> 3) % 10;
    const int tid = threadIdx.x;
    const int wid = tid >> 6;
    const int lane = tid & 63;
    const int l31 = lane & 31;
    const int hf  = lane >> 5;

    __shared__ union {
        unsigned short G[2][40 * 32 * 8];
        float S[32 * SST];
    } sm;
    __shared__ float csh[32];
    __shared__ float Mfin[32];
    __shared__ float Ifin[32];

    if (tid < 32) csh[tid] = colsum[et * 32 + tid];

    f32x16 a1, a2, a3;
#pragma unroll
    for (int r = 0; r < 16; ++r) { a1[r] = 0.f; a2[r] = 0.f; a3[r] = 0.f; }

    const float* fbase = fut + (size_t)i * NN + (size_t)(hf * 8) * N + wid * 32 + l31;
    const uint4* aHp = spH + (size_t)(et * 20) * 64 + lane;
    const uint4* aLp = spL + (size_t)(et * 20) * 64 + lane;

    for (int ts = 0; ts < 20; ++ts) {
        const float* fp = fbase + (size_t)(ts * 16) * N;
        float f[8];
#pragma unroll
        for (int m = 0; m < 8; ++m) f[m] = fp[(size_t)m * N];
        UAV bh, bl;
#pragma unroll
        for (int d = 0; d < 4; ++d) split2(f[2 * d], f[2 * d + 1], bh.u[d], bl.u[d]);
        U4V ah, al;
        ah.q = aHp[ts * 64];
        al.q = aLp[ts * 64];
        a1 = MFMA32(ah.v, bh.v, a1);
        a2 = MFMA32(al.v, bh.v, a2);
        a3 = MFMA32(ah.v, bl.v, a3);
    }

    {
        const int c  = wid * 4 + (l31 >> 3);
        const int jj = l31 & 7;
        const int sw = c & 7;
        unsigned short* GHs = sm.G[0];
        unsigned short* GLs = sm.G[1];
#pragma unroll
        for (int r = 0; r < 16; ++r) {
            int e = (r & 3) + ((r >> 2) << 3) + (hf << 2);
            float x = a1[r] + a2[r] + a3[r];
            unsigned u = __float_as_uint(x);
            float d = x - __uint_as_float(u & 0xFFFF0000u);
            int off = (c * 32 + (e ^ sw)) * 8 + jj;
            GHs[off] = (unsigned short)(u >> 16);
            GLs[off] = (unsigned short)(__float_as_uint(d) >> 16);
        }
    }
    __syncthreads();

    f32x16 p1, p2, p3;
#pragma unroll
    for (int r = 0; r < 16; ++r) { p1[r] = 0.f; p2[r] = 0.f; p3[r] = 0.f; }

    const uint4* bHp = wpH + (size_t)(wid * 20) * 64 + lane;
    const uint4* bLp = wpL + (size_t)(wid * 20) * 64 + lane;
    const unsigned short* GHs = sm.G[0];
    const unsigned short* GLs = sm.G[1];

#pragma unroll 4
    for (int ks = 0; ks < 20; ++ks) {
        int c = ks * 2 + hf;
        int off = (c * 32 + (l31 ^ (c & 7))) * 8;
        s16x8 gh = *(const s16x8*)&GHs[off];
        s16x8 gl = *(const s16x8*)&GLs[off];
        U4V wh, wl;
        wh.q = bHp[ks * 64];
        wl.q = bLp[ks * 64];
        p1 = MFMA32(gh, wh.v, p1);
        p2 = MFMA32(gl, wh.v, p2);
        p3 = MFMA32(gh, wl.v, p3);
    }

    const int jcol = wid * 32 + l31;
    float bj = bvec[jcol];
    float v[16];
#pragma unroll
    for (int r = 0; r < 16; ++r) {
        int e = (r & 3) + ((r >> 2) << 3) + (hf << 2);
        v[r] = (p1[r] + p2[r] + p3[r]) + csh[e] * bj;
    }
    __syncthreads();
#pragma unroll
    for (int r = 0; r < 16; ++r) {
        int e = (r & 3) + ((r >> 2) << 3) + (hf << 2);
        sm.S[e * SST + jcol] = v[r];
    }
    __syncthreads();
    const int hw = tid >> 5;
    const int li = tid & 31;
    if (hw < 16) {
#pragma unroll
        for (int rr = 0; rr < 2; ++rr) {
            int row = 2 * hw + rr;
            float x[10];
            float m = -3.4e38f;
#pragma unroll
            for (int q = 0; q < 10; ++q) {
                x[q] = sm.S[row * SST + li + 32 * q];
                m = fmaxf(m, x[q]);
            }
#pragma unroll
            for (int off = 16; off; off >>= 1) m = fmaxf(m, __shfl_xor(m, off, 64));
            float ssum = 0.f;
#pragma unroll
            for (int q = 0; q < 10; ++q) ssum += __expf(x[q] - m);
#pragma unroll
            for (int off = 16; off; off >>= 1) ssum += __shfl_xor(ssum, off, 64);
            if (li == 0) { Mfin[row] = m; Ifin[row] = 1.0f / ssum; }
        }
    }
    __syncthreads();
    float wcol = 0.f;
#pragma unroll
    for (int r = 0; r < 16; ++r) {
        int e = (r & 3) + ((r >> 2) << 3) + (hf << 2);
        wcol += __expf(v[r] - Mfin[e]) * Ifin[e];
    }
    wcol += __shfl_xor(wcol, 32, 64);
    if (hf == 0) atomicAdd(&w[(size_t)i * N + jcol], wcol);
}

// ---------------- out[i][k] += sum_{j in chunk} w[i][j] * s[j][k] ----------------
__global__ __launch_bounds__(320) void out_gemm_kernel(
    const float* __restrict__ w, const float* __restrict__ s,
    float* __restrict__ out)
{
    const int i = blockIdx.x;
    const int jc = blockIdx.y;
    const int k = threadIdx.x;
    const float* wr = w + (size_t)i * N + jc * 80;
    const float* sp = s + (size_t)(jc * 80) * N + k;
    float a0 = 0.f, a1 = 0.f, a2 = 0.f, a3 = 0.f;
    for (int j = 0; j < 80; j += 4) {
        a0 += wr[j + 0] * sp[(size_t)(j + 0) * N];
        a1 += wr[j + 1] * sp[(size_t)(j + 1) * N];
        a2 += wr[j + 2] * sp[(size_t)(j + 2) * N];
        a3 += wr[j + 3] * sp[(size_t)(j + 3) * N];
    }
    atomicAdd(&out[(size_t)i * N + k], (a0 + a1) + (a2 + a3));
}

extern "C" void kernel_launch(void* const* d_in, const int* in_sizes, int n_in,
                              void* d_out, int out_size, void* d_ws, size_t ws_size,
                              hipStream_t stream)
{
    const float* s    = (const float*)d_in[0];
    const float* fut  = (const float*)d_in[1];
    const float* W    = (const float*)d_in[2];
    const float* bvec = (const float*)d_in[3];
    float* out = (float*)d_out;

    char* base = (char*)d_ws;
    float* wbuf   = (float*)base;                        // 409600 B
    float* colsum = (float*)(base + 409600);             // 1280 B
    uint4* spH = (uint4*)(base + 410880);                // 204800 B
    uint4* spL = (uint4*)(base + 615680);                // 204800 B
    uint4* wpH = (uint4*)(base + 820480);                // 204800 B
    uint4* wpL = (uint4*)(base + 1025280);               // 204800 B
    uint4* GH  = (uint4*)(base + 1230080);               // 65,536,000 B
    uint4* GL  = (uint4*)(base + 1230080 + 65536000);    // 65,536,000 B
    const size_t WS_NEEDED = 1230080 + 2ull * 65536000;  // ~132.3 MB

    prep_kernel<<<dim3(302), dim3(256), 0, stream>>>(
        s, W, wbuf, out, colsum, spH, spL, wpH, wpL);

    if (ws_size >= WS_NEEDED) {
        gemm1_kernel<<<dim3(640), dim3(640), 0, stream>>>(fut, spH, spL, GH, GL);
        gemm2_kernel<<<dim3(3200), dim3(640), 0, stream>>>(
            GH, GL, wpH, wpL, bvec, colsum, wbuf);
    } else {
        fused_fb_kernel<<<dim3(3200), dim3(640), 0, stream>>>(
            fut, spH, spL, wpH, wpL, bvec, colsum, wbuf);
    }

    out_gemm_kernel<<<dim3(N, 4), dim3(320), 0, stream>>>(wbuf, s, out);
}

// Round 4
// 414.715 us; speedup vs baseline: 1.2273x; 1.2273x over previous
//
#include <hip/hip_runtime.h>
#include <hip/hip_bf16.h>
#include <math.h>

#define N 320
#define NN (N * N)          // 102400
#define SST 324             // LDS fp32 row stride for S scratch

typedef float f32x16 __attribute__((ext_vector_type(16)));
typedef short s16x8  __attribute__((ext_vector_type(8)));

#define MFMA32(a, b, c) __builtin_amdgcn_mfma_f32_32x32x16_bf16((a), (b), (c), 0, 0, 0)

union U4V { uint4 q; s16x8 v; };
union UAV { unsigned u[4]; s16x8 v; };

// truncation split: x = hi + lo with hi,lo bf16 (round-toward-zero; rel err ~2^-16 combined)
__device__ inline void split2(float x0, float x1, unsigned& hi, unsigned& lo) {
    unsigned u0 = __float_as_uint(x0), u1 = __float_as_uint(x1);
    hi = (u0 >> 16) | (u1 & 0xFFFF0000u);
    float d0 = x0 - __uint_as_float(u0 & 0xFFFF0000u);
    float d1 = x1 - __uint_as_float(u1 & 0xFFFF0000u);
    lo = (__float_as_uint(d0) >> 16) | (__float_as_uint(d1) & 0xFFFF0000u);
}

// ---------------- fused prep ----------------
// block roles:
//   [  0,100) zero wbuf
//   [100,200) zero out
//   [200,202) colsum[e] = sum_t s[t][e]
//   [202,252) pack s^T   (4 sub-blocks of 64 lanes per block)
//   [252,302) pack W^T
__global__ __launch_bounds__(256) void prep_kernel(
    const float* __restrict__ s, const float* __restrict__ W,
    float* __restrict__ wbuf, float* __restrict__ out, float* __restrict__ colsum,
    uint4* __restrict__ spH, uint4* __restrict__ spL,
    uint4* __restrict__ wpH, uint4* __restrict__ wpL)
{
    const int bid = blockIdx.x;
    const int tid = threadIdx.x;
    if (bid < 100) {
        ((float4*)wbuf)[bid * 256 + tid] = make_float4(0.f, 0.f, 0.f, 0.f);
    } else if (bid < 200) {
        ((float4*)out)[(bid - 100) * 256 + tid] = make_float4(0.f, 0.f, 0.f, 0.f);
    } else if (bid < 202) {
        int e = (bid - 200) * 256 + tid;
        if (e < N) {
            const float* sp = s + e;
            float a[8];
#pragma unroll
            for (int u = 0; u < 8; ++u) a[u] = 0.f;
            for (int t = 0; t < N; t += 8) {
#pragma unroll
                for (int u = 0; u < 8; ++u) a[u] += sp[(size_t)(t + u) * N];
            }
            colsum[e] = ((a[0] + a[1]) + (a[2] + a[3])) + ((a[4] + a[5]) + (a[6] + a[7]));
        }
    } else if (bid < 252) {
        int sub = (bid - 202) * 4 + (tid >> 6);     // 0..199 = et*20 + ts
        int l = tid & 63;
        int et = sub / 20, ts = sub % 20;
        int e = et * 32 + (l & 31);
        int t0 = ts * 16 + (l >> 5) * 8;
        unsigned hi[4], lo[4];
#pragma unroll
        for (int d = 0; d < 4; ++d)
            split2(s[(size_t)(t0 + 2 * d) * N + e], s[(size_t)(t0 + 2 * d + 1) * N + e],
                   hi[d], lo[d]);
        spH[sub * 64 + l] = make_uint4(hi[0], hi[1], hi[2], hi[3]);
        spL[sub * 64 + l] = make_uint4(lo[0], lo[1], lo[2], lo[3]);
    } else {
        int sub = (bid - 252) * 4 + (tid >> 6);     // 0..199 = jt*20 + ks
        int l = tid & 63;
        int jt = sub / 20, ks = sub % 20;
        int j = jt * 32 + (l & 31);
        int k0 = ks * 16 + (l >> 5) * 8;
        const float* wr = W + (size_t)j * N + k0;
        unsigned hi[4], lo[4];
#pragma unroll
        for (int d = 0; d < 4; ++d) split2(wr[2 * d], wr[2 * d + 1], hi[d], lo[d]);
        wpH[sub * 64 + l] = make_uint4(hi[0], hi[1], hi[2], hi[3]);
        wpL[sub * 64 + l] = make_uint4(lo[0], lo[1], lo[2], lo[3]);
    }
}

// ---------------- fused5: per (i, e-quarter 64) — F redundancy 5x (was 10x) ----------
// bid decode: x = bid&7 (XCD), g = bid>>3; iw = g/5, eq = g%5; i = iw*8 + x.
// The 5 eq-blocks of one i land at bids spaced 8 apart -> co-resident on one XCD,
// so F_i is served from that XCD's L2 after first touch.
// Phase A: two single-chain 32x32 accumulators (e-slabs 2eq, 2eq+1) per wave.
// Phase B + softmax run twice (once per slab), reusing the 40KB LDS G-buffer.
__global__ __launch_bounds__(640, 5) void fused5_kernel(
    const float* __restrict__ fut,
    const uint4* __restrict__ spH, const uint4* __restrict__ spL,
    const uint4* __restrict__ wpH, const uint4* __restrict__ wpL,
    const float* __restrict__ bvec, const float* __restrict__ colsum,
    float* __restrict__ w)
{
    const int bid = blockIdx.x;
    const int x  = bid & 7;
    const int g  = bid >> 3;
    const int iw = g / 5, eq = g % 5;
    const int i  = iw * 8 + x;
    const int tid = threadIdx.x;
    const int wid = tid >> 6;         // wave 0..9 = 32-wide j column tile
    const int lane = tid & 63;
    const int l31 = lane & 31;
    const int hf  = lane >> 5;

    // G in LDS: frag-linear, XOR-swizzled 16B chunks (proven layout, 0 conflicts).
    __shared__ union {
        unsigned short G[2][40 * 32 * 8];   // [hi/lo] 20KB each
        float S[32 * SST];                  // softmax scratch
    } sm;
    __shared__ float csh[64];
    __shared__ float Mfin[32];
    __shared__ float Ifin[32];

    if (tid < 64) csh[tid] = colsum[eq * 64 + tid];

    // ---------------- phase A: G[2 slabs] = s^T @ F_i (column tile wid) -----------
    f32x16 acc0, acc1;
#pragma unroll
    for (int r = 0; r < 16; ++r) { acc0[r] = 0.f; acc1[r] = 0.f; }

    const float* fbase = fut + (size_t)i * NN + (size_t)(hf * 8) * N + wid * 32 + l31;
    const uint4* aH0 = spH + (size_t)((eq * 2 + 0) * 20) * 64 + lane;
    const uint4* aL0 = spL + (size_t)((eq * 2 + 0) * 20) * 64 + lane;
    const uint4* aH1 = spH + (size_t)((eq * 2 + 1) * 20) * 64 + lane;
    const uint4* aL1 = spL + (size_t)((eq * 2 + 1) * 20) * 64 + lane;

#pragma unroll 2
    for (int ts = 0; ts < 20; ++ts) {
        const float* fp = fbase + (size_t)(ts * 16) * N;
        float f[8];
#pragma unroll
        for (int m = 0; m < 8; ++m) f[m] = fp[(size_t)m * N];
        UAV bh, bl;
#pragma unroll
        for (int d = 0; d < 4; ++d) split2(f[2 * d], f[2 * d + 1], bh.u[d], bl.u[d]);
        U4V a0h, a0l, a1h, a1l;
        a0h.q = aH0[ts * 64]; a0l.q = aL0[ts * 64];
        a1h.q = aH1[ts * 64]; a1l.q = aL1[ts * 64];
        acc0 = MFMA32(a0h.v, bh.v, acc0);
        acc1 = MFMA32(a1h.v, bh.v, acc1);
        acc0 = MFMA32(a0l.v, bh.v, acc0);
        acc1 = MFMA32(a1l.v, bh.v, acc1);
        acc0 = MFMA32(a0h.v, bl.v, acc0);
        acc1 = MFMA32(a1h.v, bl.v, acc1);
    }

    const uint4* bHp = wpH + (size_t)(wid * 20) * 64 + lane;
    const uint4* bLp = wpL + (size_t)(wid * 20) * 64 + lane;
    const int jcol = wid * 32 + l31;
    const float bj = bvec[jcol];
    const int hw = tid >> 5;
    const int li = tid & 31;
    float wcol = 0.f;

    // per-slab: G->LDS, phase B GEMM, softmax, accumulate wcol
    auto doSlab = [&](const f32x16& acc, const int slab) {
        // G -> LDS bf16 hi/lo in frag-linear swizzled layout
        {
            const int c  = wid * 4 + (l31 >> 3);
            const int jj = l31 & 7;
            const int sw = c & 7;
            unsigned short* GH = sm.G[0];
            unsigned short* GL = sm.G[1];
#pragma unroll
            for (int r = 0; r < 16; ++r) {
                int e = (r & 3) + ((r >> 2) << 3) + (hf << 2);
                float xv = acc[r];
                unsigned u = __float_as_uint(xv);
                float d = xv - __uint_as_float(u & 0xFFFF0000u);
                int off = (c * 32 + (e ^ sw)) * 8 + jj;
                GH[off] = (unsigned short)(u >> 16);
                GL[off] = (unsigned short)(__float_as_uint(d) >> 16);
            }
        }
        __syncthreads();   // Ba: G (and csh on slab 0) visible

        // phase B: S = G @ W^T (+ colsum*b)
        f32x16 p;
#pragma unroll
        for (int r = 0; r < 16; ++r) p[r] = 0.f;
        const unsigned short* GH = sm.G[0];
        const unsigned short* GL = sm.G[1];
#pragma unroll 4
        for (int ks = 0; ks < 20; ++ks) {
            int c = ks * 2 + hf;
            int off = (c * 32 + (l31 ^ (c & 7))) * 8;
            s16x8 gh = *(const s16x8*)&GH[off];
            s16x8 gl = *(const s16x8*)&GL[off];
            U4V wh, wl;
            wh.q = bHp[ks * 64];
            wl.q = bLp[ks * 64];
            p = MFMA32(gh, wh.v, p);
            p = MFMA32(gl, wh.v, p);
            p = MFMA32(gh, wl.v, p);
        }

        float v[16];
#pragma unroll
        for (int r = 0; r < 16; ++r) {
            int e = (r & 3) + ((r >> 2) << 3) + (hf << 2);
            v[r] = p[r] + csh[slab * 32 + e] * bj;
        }
        __syncthreads();   // Bb: all waves done reading G before S overwrites union

#pragma unroll
        for (int r = 0; r < 16; ++r) {
            int e = (r & 3) + ((r >> 2) << 3) + (hf << 2);
            sm.S[e * SST + jcol] = v[r];
        }
        __syncthreads();   // Bc

        // row sweeps: half-wave hw (0..15) handles rows 2hw, 2hw+1
        if (hw < 16) {
#pragma unroll
            for (int rr = 0; rr < 2; ++rr) {
                int row = 2 * hw + rr;
                float xr[10];
                float m = -3.4e38f;
#pragma unroll
                for (int q = 0; q < 10; ++q) {
                    xr[q] = sm.S[row * SST + li + 32 * q];
                    m = fmaxf(m, xr[q]);
                }
#pragma unroll
                for (int off = 16; off; off >>= 1) m = fmaxf(m, __shfl_xor(m, off, 64));
                float ssum = 0.f;
#pragma unroll
                for (int q = 0; q < 10; ++q) ssum += __expf(xr[q] - m);
#pragma unroll
                for (int off = 16; off; off >>= 1) ssum += __shfl_xor(ssum, off, 64);
                if (li == 0) { Mfin[row] = m; Ifin[row] = 1.0f / ssum; }
            }
        }
        __syncthreads();   // Bd

#pragma unroll
        for (int r = 0; r < 16; ++r) {
            int e = (r & 3) + ((r >> 2) << 3) + (hf << 2);
            wcol += __expf(v[r] - Mfin[e]) * Ifin[e];
        }
        // Next slab's G-write starts after Bd and touches only the S/G union;
        // Mfin/Ifin are not overwritten until after the next slab's Bc -> safe.
    };

    doSlab(acc0, 0);
    doSlab(acc1, 1);

    wcol += __shfl_xor(wcol, 32, 64);
    if (hf == 0) atomicAdd(&w[(size_t)i * N + jcol], wcol);
}

// ---------------- out[i][k] += sum_{j in chunk} w[i][j] * s[j][k] ----------------
__global__ __launch_bounds__(320) void out_gemm_kernel(
    const float* __restrict__ w, const float* __restrict__ s,
    float* __restrict__ out)
{
    const int i = blockIdx.x;
    const int jc = blockIdx.y;
    const int k = threadIdx.x;
    const float* wr = w + (size_t)i * N + jc * 80;
    const float* sp = s + (size_t)(jc * 80) * N + k;
    float a0 = 0.f, a1 = 0.f, a2 = 0.f, a3 = 0.f;
    for (int j = 0; j < 80; j += 4) {
        a0 += wr[j + 0] * sp[(size_t)(j + 0) * N];
        a1 += wr[j + 1] * sp[(size_t)(j + 1) * N];
        a2 += wr[j + 2] * sp[(size_t)(j + 2) * N];
        a3 += wr[j + 3] * sp[(size_t)(j + 3) * N];
    }
    atomicAdd(&out[(size_t)i * N + k], (a0 + a1) + (a2 + a3));
}

extern "C" void kernel_launch(void* const* d_in, const int* in_sizes, int n_in,
                              void* d_out, int out_size, void* d_ws, size_t ws_size,
                              hipStream_t stream)
{
    const float* s    = (const float*)d_in[0];
    const float* fut  = (const float*)d_in[1];
    const float* W    = (const float*)d_in[2];
    const float* bvec = (const float*)d_in[3];
    float* out = (float*)d_out;

    char* base = (char*)d_ws;
    float* wbuf   = (float*)base;                        // 409600 B
    float* colsum = (float*)(base + 409600);             // 1280 B
    uint4* spH = (uint4*)(base + 410880);                // 204800 B
    uint4* spL = (uint4*)(base + 615680);                // 204800 B
    uint4* wpH = (uint4*)(base + 820480);                // 204800 B
    uint4* wpL = (uint4*)(base + 1025280);               // 204800 B

    prep_kernel<<<dim3(302), dim3(256), 0, stream>>>(
        s, W, wbuf, out, colsum, spH, spL, wpH, wpL);

    fused5_kernel<<<dim3(1600), dim3(640), 0, stream>>>(
        fut, spH, spL, wpH, wpL, bvec, colsum, wbuf);

    out_gemm_kernel<<<dim3(N, 4), dim3(320), 0, stream>>>(wbuf, s, out);
}